// Round 4
// baseline (717.003 us; speedup 1.0000x reference)
//
#include <hip/hip_runtime.h>
#include <hip/hip_bf16.h>
#include <math.h>

#define NPTS 1000000
#define NPATCH 4096
#define BM 128
#define NCOPY 64

typedef float f32x4 __attribute__((ext_vector_type(4)));
typedef __bf16 bf16x8 __attribute__((ext_vector_type(8)));
typedef __bf16 bf16x4 __attribute__((ext_vector_type(4)));

// ---- module-scope scratch: no dependence on d_ws ----------------------------
__device__ __align__(16) float  g_acc4[NPATCH * 4];           // 64 KB
__device__ __align__(16) __bf16 g_w2f[4096];                  // fragment-major
__device__ __align__(16) __bf16 g_pwf[4096];
__device__ __align__(16) float  g_part[NCOPY * NPATCH * 4];   // 4 MB replicated accum

// -------- prep: blocks 0,1 transpose W2/pwW to fragment-major bf16;
//          blocks 2..257 zero g_part (graph replays need re-zero every launch)
__global__ __launch_bounds__(256) void prep(const float* __restrict__ W2,
                                            const float* __restrict__ pwW) {
    const int b = blockIdx.x, tid = threadIdx.x;
    if (b < 2) {
        const float* src = (b == 0) ? W2 : pwW;
        __bf16* dst = (b == 0) ? g_w2f : g_pwf;
        for (int e = tid; e < 4096; e += 256) {
            int j = e & 7, lane = (e >> 3) & 63, ft = e >> 9;
            int ks = ft >> 2, t = ft & 3, q = lane >> 4, ln = lane & 15;
            // dst[((ks*4+t)*64+lane)*8+j] = W[k=ks*32+q*8+j][n=t*16+ln]
            dst[e] = (__bf16)src[(ks * 32 + q * 8 + j) * 64 + t * 16 + ln];
        }
    } else {
        f32x4 z = {0.f, 0.f, 0.f, 0.f};
        int base = (b - 2) * 1024;  // f32x4 units; 256 blocks x 1024 = 256K f32x4 = 4MB
        #pragma unroll
        for (int u = 0; u < 4; ++u)
            ((f32x4*)g_part)[base + u * 256 + tid] = z;
    }
}

// -------- patch sums: fire-and-forget atomics into 64 replicated copies ------
__global__ __launch_bounds__(256) void patch_scatter(const float* __restrict__ coord,
                                                     const int* __restrict__ ids) {
    const int NG = NPTS / 4;  // 250000 quad-groups
    float* dst = g_part + (size_t)(blockIdx.x & (NCOPY - 1)) * (NPATCH * 4);
    for (int g = blockIdx.x * 256 + threadIdx.x; g < NG; g += gridDim.x * 256) {
        int4 id4 = ((const int4*)ids)[g];
        f32x4 c0 = ((const f32x4*)coord)[3 * g + 0];
        f32x4 c1 = ((const f32x4*)coord)[3 * g + 1];
        f32x4 c2 = ((const f32x4*)coord)[3 * g + 2];
        atomicAdd(&dst[4 * id4.x + 0], c0.x); atomicAdd(&dst[4 * id4.x + 1], c0.y);
        atomicAdd(&dst[4 * id4.x + 2], c0.z); atomicAdd(&dst[4 * id4.x + 3], 1.0f);
        atomicAdd(&dst[4 * id4.y + 0], c0.w); atomicAdd(&dst[4 * id4.y + 1], c1.x);
        atomicAdd(&dst[4 * id4.y + 2], c1.y); atomicAdd(&dst[4 * id4.y + 3], 1.0f);
        atomicAdd(&dst[4 * id4.z + 0], c1.z); atomicAdd(&dst[4 * id4.z + 1], c1.w);
        atomicAdd(&dst[4 * id4.z + 2], c2.x); atomicAdd(&dst[4 * id4.z + 3], 1.0f);
        atomicAdd(&dst[4 * id4.w + 0], c2.y); atomicAdd(&dst[4 * id4.w + 1], c2.z);
        atomicAdd(&dst[4 * id4.w + 2], c2.w); atomicAdd(&dst[4 * id4.w + 3], 1.0f);
    }
}

// -------- reduce 64 copies -> interleaved acc4 {sx,sy,sz,cnt} ----------------
__global__ __launch_bounds__(256) void patch_reduce() {
    int j = blockIdx.x * 256 + threadIdx.x;  // 0..16383
    float s = 0.f;
    #pragma unroll 8
    for (int k = 0; k < NCOPY; ++k)
        s += g_part[(size_t)k * NPATCH * 4 + j];
    g_acc4[j] = s;
}

// -------- main fused kernel: ONE barrier, per-wave-independent ---------------
// Each lane computes exactly the h values its MFMA B-fragments need -> h stays
// in registers (no LDS, no barrier). y exchange is among the 4 q-lanes of the
// same wave -> per-wave-private LDS region, lgkmcnt-ordered, no barrier.
__global__ __launch_bounds__(256) void cpe_main(
    const float* __restrict__ x, const float* __restrict__ coord,
    const int* __restrict__ ids,
    const float* __restrict__ W1, const float* __restrict__ b1,
    const float* __restrict__ b2,
    const float* __restrict__ dww, const float* __restrict__ dwb,
    const float* __restrict__ pwb,
    const float* __restrict__ lng, const float* __restrict__ lnb,
    float* __restrict__ out) {

    __shared__ __align__(16) __bf16 sY[4 * 2048];  // per-wave 32pts x 64ch, granule-major
    __shared__ float sW1[192];
    __shared__ __align__(16) float sb1[64], sb2[64], sdww[64], sdwb[64],
                                   spwb[64], slng[64], slnb[64];

    const int tid = threadIdx.x, lane = tid & 63, wave = tid >> 6;
    const int q = lane >> 4, ln = lane & 15;
    const int block0 = blockIdx.x * BM;
    const int P0 = block0 + wave * 32 + ln;  // lane's first point

    // ---- x prefetch issued first: whole kernel to hide HBM latency ----
    f32x4 xv[2][4];
    #pragma unroll
    for (int m = 0; m < 2; ++m) {
        int gp = P0 + m * 16;
        const float* xr = x + (size_t)gp * 64 + q * 4;
        #pragma unroll
        for (int t = 0; t < 4; ++t)
            xv[m][t] = (gp < NPTS) ? *(const f32x4*)(xr + t * 16)
                                   : (f32x4){0.f, 0.f, 0.f, 0.f};
    }

    // ---- stage params (the only barrier in the kernel) ----
    if (tid < 192) sW1[tid] = W1[tid];
    if (tid < 64) {
        sb1[tid] = b1[tid];  sb2[tid] = b2[tid];
        sdww[tid] = dww[tid]; sdwb[tid] = dwb[tid];
        spwb[tid] = pwb[tid]; slng[tid] = lng[tid]; slnb[tid] = lnb[tid];
    }
    __syncthreads();

    // ---- gather centers + deltas for this lane's 2 points (4x q-redundant:
    //      same-address loads broadcast) ----
    float dx[2], dy[2], dz[2];
    #pragma unroll
    for (int m = 0; m < 2; ++m) {
        int gp = P0 + m * 16;
        dx[m] = dy[m] = dz[m] = 0.f;
        if (gp < NPTS) {
            int pid = ids[gp];
            f32x4 a = ((const f32x4*)g_acc4)[pid];
            float invc = 1.0f / fmaxf(a.w, 1.0f);
            dx[m] = coord[3 * gp + 0] - a.x * invc;
            dy[m] = coord[3 * gp + 1] - a.y * invc;
            dz[m] = coord[3 * gp + 2] - a.z * invc;
        }
    }

    // ---- MLP 3->64 (exact-erf GELU) directly into register B-fragments ----
    // hfr[m][ks][j] = h[P0+m*16][ks*32 + q*8 + j]
    bf16x8 hfr[2][2];
    #pragma unroll
    for (int m = 0; m < 2; ++m)
        #pragma unroll
        for (int ks = 0; ks < 2; ++ks)
            #pragma unroll
            for (int j = 0; j < 8; ++j) {
                int c = ks * 32 + q * 8 + j;
                float v = sb1[c] + dx[m] * sW1[c] + dy[m] * sW1[64 + c] + dz[m] * sW1[128 + c];
                v = 0.5f * v * (1.0f + erff(v * 0.70710678118654752f));
                hfr[m][ks][j] = (__bf16)v;
            }

    // ---- GEMM1: acc[m][t][r] = pos[P0+m*16][t*16+q*4+r] ----
    f32x4 acc[2][4];
    #pragma unroll
    for (int m = 0; m < 2; ++m)
        #pragma unroll
        for (int t = 0; t < 4; ++t)
            acc[m][t] = (f32x4){0.f, 0.f, 0.f, 0.f};

    #pragma unroll
    for (int ks = 0; ks < 2; ++ks) {
        bf16x8 wf[4];
        #pragma unroll
        for (int t = 0; t < 4; ++t)
            wf[t] = *(const bf16x8*)&g_w2f[((ks * 4 + t) * 64 + lane) * 8];
        #pragma unroll
        for (int m = 0; m < 2; ++m)
            #pragma unroll
            for (int t = 0; t < 4; ++t)
                acc[m][t] = __builtin_amdgcn_mfma_f32_16x16x32_bf16(wf[t], hfr[m][ks], acc[m][t], 0, 0, 0);
    }

    // ---- epilogue1: o = x + pos + b2; y = o*dww + dwb -> per-wave LDS ----
    __bf16* wy = &sY[wave * 2048];
    #pragma unroll
    for (int m = 0; m < 2; ++m)
        #pragma unroll
        for (int t = 0; t < 4; ++t) {
            int c0 = t * 16 + q * 4;
            f32x4 o = xv[m][t] + acc[m][t] + *(const f32x4*)&sb2[c0];
            f32x4 y = o * *(const f32x4*)&sdww[c0] + *(const f32x4*)&sdwb[c0];
            bf16x4 yb;
            #pragma unroll
            for (int j = 0; j < 4; ++j) yb[j] = (__bf16)y[j];
            int g = 2 * t + (q >> 1);
            *(bf16x4*)&wy[g * 256 + (m * 16 + ln) * 8 + (q & 1) * 4] = yb;
        }
    // (intra-wave LDS dependency: compiler inserts lgkmcnt wait; no barrier)

    // ---- GEMM2: o = (y @ pw_W)^T ----
    #pragma unroll
    for (int m = 0; m < 2; ++m)
        #pragma unroll
        for (int t = 0; t < 4; ++t)
            acc[m][t] = (f32x4){0.f, 0.f, 0.f, 0.f};

    #pragma unroll
    for (int ks = 0; ks < 2; ++ks) {
        bf16x8 wf[4], yfr[2];
        #pragma unroll
        for (int m = 0; m < 2; ++m)
            yfr[m] = *(const bf16x8*)&wy[(ks * 4 + q) * 256 + (m * 16 + ln) * 8];
        #pragma unroll
        for (int t = 0; t < 4; ++t)
            wf[t] = *(const bf16x8*)&g_pwf[((ks * 4 + t) * 64 + lane) * 8];
        #pragma unroll
        for (int m = 0; m < 2; ++m)
            #pragma unroll
            for (int t = 0; t < 4; ++t)
                acc[m][t] = __builtin_amdgcn_mfma_f32_16x16x32_bf16(wf[t], yfr[m], acc[m][t], 0, 0, 0);
    }

    // ---- LayerNorm in registers; reduce across the 4 q-lanes via shfl ----
    #pragma unroll
    for (int m = 0; m < 2; ++m) {
        int gp = P0 + m * 16;
        f32x4 v[4];
        float s = 0.f, ss = 0.f;
        #pragma unroll
        for (int t = 0; t < 4; ++t) {
            int c0 = t * 16 + q * 4;
            v[t] = acc[m][t] + *(const f32x4*)&spwb[c0];
            #pragma unroll
            for (int j = 0; j < 4; ++j) { s += v[t][j]; ss += v[t][j] * v[t][j]; }
        }
        s += __shfl_xor(s, 16);  s += __shfl_xor(s, 32);
        ss += __shfl_xor(ss, 16); ss += __shfl_xor(ss, 32);
        float mu = s * (1.0f / 64.0f);
        float rs = rsqrtf(ss * (1.0f / 64.0f) - mu * mu + 1e-5f);
        if (gp < NPTS) {
            float* op = out + (size_t)gp * 64;
            #pragma unroll
            for (int t = 0; t < 4; ++t) {
                int c0 = t * 16 + q * 4;
                f32x4 g = *(const f32x4*)&slng[c0];
                f32x4 b = *(const f32x4*)&slnb[c0];
                f32x4 o = (v[t] - mu) * rs * g + b;
                __builtin_nontemporal_store(o, (f32x4*)(op + c0));
            }
        }
    }
}

extern "C" void kernel_launch(void* const* d_in, const int* in_sizes, int n_in,
                              void* d_out, int out_size, void* d_ws, size_t ws_size,
                              hipStream_t stream) {
    const float* x     = (const float*)d_in[0];
    const float* coord = (const float*)d_in[1];
    const int*   ids   = (const int*)d_in[2];
    const float* W1    = (const float*)d_in[3];
    const float* b1    = (const float*)d_in[4];
    const float* W2    = (const float*)d_in[5];
    const float* b2    = (const float*)d_in[6];
    const float* dww   = (const float*)d_in[7];
    const float* dwb   = (const float*)d_in[8];
    const float* pwW   = (const float*)d_in[9];
    const float* pwb   = (const float*)d_in[10];
    const float* lng   = (const float*)d_in[11];
    const float* lnb   = (const float*)d_in[12];
    float* outp = (float*)d_out;
    (void)d_ws; (void)ws_size;

    prep<<<258, 256, 0, stream>>>(W2, pwW);
    patch_scatter<<<1024, 256, 0, stream>>>(coord, ids);
    patch_reduce<<<NPATCH * 4 / 256, 256, 0, stream>>>();
    cpe_main<<<(NPTS + BM - 1) / BM, 256, 0, stream>>>(
        x, coord, ids, W1, b1, b2, dww, dwb, pwb, lng, lnb, outp);
}

// Round 5
// 534.878 us; speedup vs baseline: 1.3405x; 1.3405x over previous
//
#include <hip/hip_runtime.h>
#include <hip/hip_bf16.h>
#include <math.h>

#define NPTS 1000000
#define NPATCH 4096
#define BM 64                 // points per block; NPTS/BM = 15625 exact

typedef float f32x4 __attribute__((ext_vector_type(4)));
typedef __bf16 bf16x8 __attribute__((ext_vector_type(8)));
typedef __bf16 bf16x4 __attribute__((ext_vector_type(4)));

#define PB_BLOCKS 500
#define PB_PTS (NPTS / PB_BLOCKS)   // 2000 exact
#define PB_G (PB_PTS / 4)           // 500 quad-groups per block

// ---- module-scope scratch: no dependence on d_ws ----------------------------
__device__ __align__(16) float  g_acc4[NPATCH * 4];              // 64 KB
__device__ __align__(16) __bf16 g_w2f[4096];                     // fragment-major
__device__ __align__(16) __bf16 g_pwf[4096];
__device__ __align__(16) float  g_part[PB_BLOCKS * NPATCH * 4];  // 32 MB partials

// -------- one-time: W2 / pwW -> bf16 fragment-major --------------------------
// dst[((ks*4+t)*64+lane)*8+j] = W[k=ks*32+(lane>>4)*8+j][n=t*16+(lane&15)]
__global__ __launch_bounds__(256) void prep(const float* __restrict__ W2,
                                            const float* __restrict__ pwW) {
    const float* src = (blockIdx.x == 0) ? W2 : pwW;
    __bf16* dst = (blockIdx.x == 0) ? g_w2f : g_pwf;
    for (int e = threadIdx.x; e < 4096; e += 256) {
        int j = e & 7, lane = (e >> 3) & 63, ft = e >> 9;
        int ks = ft >> 2, t = ft & 3, q = lane >> 4, ln = lane & 15;
        dst[e] = (__bf16)src[(ks * 32 + q * 8 + j) * 64 + t * 16 + ln];
    }
}

// -------- patch sums: LDS histogram (plane-major) -> non-atomic partial dump -
__global__ __launch_bounds__(256) void patch_partial(const float* __restrict__ coord,
                                                     const int* __restrict__ ids) {
    __shared__ float lacc[4 * NPATCH];  // [comp][patch]
    for (int j = threadIdx.x; j < 4 * NPATCH; j += 256) lacc[j] = 0.0f;
    __syncthreads();
    const int g0 = blockIdx.x * PB_G;
    for (int g = g0 + threadIdx.x; g < g0 + PB_G; g += 256) {
        int4 id4 = ((const int4*)ids)[g];
        f32x4 c0 = ((const f32x4*)coord)[3 * g + 0];
        f32x4 c1 = ((const f32x4*)coord)[3 * g + 1];
        f32x4 c2 = ((const f32x4*)coord)[3 * g + 2];
        atomicAdd(&lacc[0 * NPATCH + id4.x], c0.x);
        atomicAdd(&lacc[1 * NPATCH + id4.x], c0.y);
        atomicAdd(&lacc[2 * NPATCH + id4.x], c0.z);
        atomicAdd(&lacc[3 * NPATCH + id4.x], 1.0f);
        atomicAdd(&lacc[0 * NPATCH + id4.y], c0.w);
        atomicAdd(&lacc[1 * NPATCH + id4.y], c1.x);
        atomicAdd(&lacc[2 * NPATCH + id4.y], c1.y);
        atomicAdd(&lacc[3 * NPATCH + id4.y], 1.0f);
        atomicAdd(&lacc[0 * NPATCH + id4.z], c1.z);
        atomicAdd(&lacc[1 * NPATCH + id4.z], c1.w);
        atomicAdd(&lacc[2 * NPATCH + id4.z], c2.x);
        atomicAdd(&lacc[3 * NPATCH + id4.z], 1.0f);
        atomicAdd(&lacc[0 * NPATCH + id4.w], c2.y);
        atomicAdd(&lacc[1 * NPATCH + id4.w], c2.z);
        atomicAdd(&lacc[2 * NPATCH + id4.w], c2.w);
        atomicAdd(&lacc[3 * NPATCH + id4.w], 1.0f);
    }
    __syncthreads();
    // dump interleaved {sx,sy,sz,cnt} -> coalesced reduce reads
    float* dst = g_part + (size_t)blockIdx.x * 4 * NPATCH;
    for (int j = threadIdx.x; j < 4 * NPATCH; j += 256) {
        int p = j >> 2, c = j & 3;
        dst[j] = lacc[c * NPATCH + p];
    }
}

// -------- reduce partials -> interleaved acc4 --------------------------------
__global__ __launch_bounds__(256) void patch_reduce() {
    int j = blockIdx.x * 256 + threadIdx.x;  // 0..16383
    float s = 0.f;
    #pragma unroll 10
    for (int k = 0; k < PB_BLOCKS; ++k)
        s += g_part[(size_t)k * NPATCH * 4 + j];
    g_acc4[j] = s;
}

// -------- main fused kernel: 1 point/lane, 1 barrier, minimal live state -----
// h never touches LDS (each lane computes its own MFMA B-fragment values).
// y exchange: per-wave-private 2KB LDS region, lgkmcnt-ordered, no barrier.
__global__ __launch_bounds__(256, 8) void cpe_main(
    const float* __restrict__ x, const float* __restrict__ coord,
    const int* __restrict__ ids,
    const float* __restrict__ W1, const float* __restrict__ b1,
    const float* __restrict__ b2,
    const float* __restrict__ dww, const float* __restrict__ dwb,
    const float* __restrict__ pwb,
    const float* __restrict__ lng, const float* __restrict__ lnb,
    float* __restrict__ out) {

    __shared__ __align__(16) __bf16 sY[4 * 1024];  // 4 waves x (16 pts x 64 ch)
    __shared__ float sW1[192];
    __shared__ __align__(16) float sb1[64], sb2[64], sdww[64], sdwb[64],
                                   spwb[64], slng[64], slnb[64];

    const int tid = threadIdx.x, lane = tid & 63, wave = tid >> 6;
    const int q = lane >> 4, ln = lane & 15;
    const int P = blockIdx.x * BM + wave * 16 + ln;  // this lane's point (always < NPTS)

    // ---- stage params (the only barrier) ----
    if (tid < 192) sW1[tid] = W1[tid];
    if (tid < 64) {
        sb1[tid] = b1[tid];  sb2[tid] = b2[tid];
        sdww[tid] = dww[tid]; sdwb[tid] = dwb[tid];
        spwb[tid] = pwb[tid]; slng[tid] = lng[tid]; slnb[tid] = lnb[tid];
    }
    __syncthreads();

    // ---- delta for P (4x q-redundant; same-address loads broadcast) ----
    int pid = ids[P];
    f32x4 a = ((const f32x4*)g_acc4)[pid];
    float invc = 1.0f / fmaxf(a.w, 1.0f);
    float dx = coord[3 * P + 0] - a.x * invc;
    float dy = coord[3 * P + 1] - a.y * invc;
    float dz = coord[3 * P + 2] - a.z * invc;

    // ---- MLP 3->64 (exact-erf GELU) directly into this lane's B-fragments ----
    // hfr[ks][j] = h[P][ks*32 + q*8 + j]
    bf16x8 hfr[2];
    #pragma unroll
    for (int ks = 0; ks < 2; ++ks)
        #pragma unroll
        for (int j = 0; j < 8; ++j) {
            int c = ks * 32 + q * 8 + j;
            float v = sb1[c] + dx * sW1[c] + dy * sW1[64 + c] + dz * sW1[128 + c];
            v = 0.5f * v * (1.0f + erff(v * 0.70710678118654752f));
            hfr[ks][j] = (__bf16)v;
        }

    // ---- GEMM1: acc[t][r] = pos[P][t*16 + q*4 + r] ----
    f32x4 acc[4];
    #pragma unroll
    for (int t = 0; t < 4; ++t) acc[t] = (f32x4){0.f, 0.f, 0.f, 0.f};
    #pragma unroll
    for (int ks = 0; ks < 2; ++ks) {
        bf16x8 wf[4];
        #pragma unroll
        for (int t = 0; t < 4; ++t)
            wf[t] = *(const bf16x8*)&g_w2f[((ks * 4 + t) * 64 + lane) * 8];
        #pragma unroll
        for (int t = 0; t < 4; ++t)
            acc[t] = __builtin_amdgcn_mfma_f32_16x16x32_bf16(wf[t], hfr[ks], acc[t], 0, 0, 0);
    }

    // ---- x load: short live range; TLP hides latency at high occupancy ----
    f32x4 xv[4];
    {
        const float* xr = x + (size_t)P * 64 + q * 4;
        #pragma unroll
        for (int t = 0; t < 4; ++t) xv[t] = *(const f32x4*)(xr + t * 16);
    }

    // ---- epilogue1: o = x + pos + b2; y = o*dww + dwb -> per-wave LDS ----
    __bf16* wy = &sY[wave * 1024];
    #pragma unroll
    for (int t = 0; t < 4; ++t) {
        int c0 = t * 16 + q * 4;
        f32x4 o = xv[t] + acc[t] + *(const f32x4*)&sb2[c0];
        f32x4 y = o * *(const f32x4*)&sdww[c0] + *(const f32x4*)&sdwb[c0];
        bf16x4 yb;
        #pragma unroll
        for (int j = 0; j < 4; ++j) yb[j] = (__bf16)y[j];
        *(bf16x4*)&wy[(2 * t + (q >> 1)) * 128 + ln * 8 + (q & 1) * 4] = yb;
    }
    // intra-wave LDS dependency -> compiler inserts lgkmcnt wait; no barrier

    // ---- GEMM2: acc[t][r] = (y @ pw_W)[P][t*16 + q*4 + r] ----
    #pragma unroll
    for (int t = 0; t < 4; ++t) acc[t] = (f32x4){0.f, 0.f, 0.f, 0.f};
    #pragma unroll
    for (int ks = 0; ks < 2; ++ks) {
        bf16x8 yfr = *(const bf16x8*)&wy[(ks * 4 + q) * 128 + ln * 8];
        bf16x8 wf[4];
        #pragma unroll
        for (int t = 0; t < 4; ++t)
            wf[t] = *(const bf16x8*)&g_pwf[((ks * 4 + t) * 64 + lane) * 8];
        #pragma unroll
        for (int t = 0; t < 4; ++t)
            acc[t] = __builtin_amdgcn_mfma_f32_16x16x32_bf16(wf[t], yfr, acc[t], 0, 0, 0);
    }

    // ---- LayerNorm in registers; reduce across the 4 q-lanes via shfl ----
    f32x4 v[4];
    float s = 0.f, ss = 0.f;
    #pragma unroll
    for (int t = 0; t < 4; ++t) {
        int c0 = t * 16 + q * 4;
        v[t] = acc[t] + *(const f32x4*)&spwb[c0];
        #pragma unroll
        for (int j = 0; j < 4; ++j) { s += v[t][j]; ss += v[t][j] * v[t][j]; }
    }
    s += __shfl_xor(s, 16);  s += __shfl_xor(s, 32);
    ss += __shfl_xor(ss, 16); ss += __shfl_xor(ss, 32);
    float mu = s * (1.0f / 64.0f);
    float rs = rsqrtf(ss * (1.0f / 64.0f) - mu * mu + 1e-5f);
    float* op = out + (size_t)P * 64;
    #pragma unroll
    for (int t = 0; t < 4; ++t) {
        int c0 = t * 16 + q * 4;
        f32x4 g = *(const f32x4*)&slng[c0];
        f32x4 b = *(const f32x4*)&slnb[c0];
        *(f32x4*)(op + c0) = (v[t] - mu) * rs * g + b;
    }
}

extern "C" void kernel_launch(void* const* d_in, const int* in_sizes, int n_in,
                              void* d_out, int out_size, void* d_ws, size_t ws_size,
                              hipStream_t stream) {
    const float* x     = (const float*)d_in[0];
    const float* coord = (const float*)d_in[1];
    const int*   ids   = (const int*)d_in[2];
    const float* W1    = (const float*)d_in[3];
    const float* b1    = (const float*)d_in[4];
    const float* W2    = (const float*)d_in[5];
    const float* b2    = (const float*)d_in[6];
    const float* dww   = (const float*)d_in[7];
    const float* dwb   = (const float*)d_in[8];
    const float* pwW   = (const float*)d_in[9];
    const float* pwb   = (const float*)d_in[10];
    const float* lng   = (const float*)d_in[11];
    const float* lnb   = (const float*)d_in[12];
    float* outp = (float*)d_out;
    (void)d_ws; (void)ws_size;

    prep<<<2, 256, 0, stream>>>(W2, pwW);
    patch_partial<<<PB_BLOCKS, 256, 0, stream>>>(coord, ids);
    patch_reduce<<<NPATCH * 4 / 256, 256, 0, stream>>>();
    cpe_main<<<NPTS / BM, 256, 0, stream>>>(
        x, coord, ids, W1, b1, b2, dww, dwb, pwb, lng, lnb, outp);
}